// Round 2
// baseline (702.397 us; speedup 1.0000x reference)
//
#include <hip/hip_runtime.h>
#include <math.h>

// CTC loss (normalized forward/backward) for B=128, C=512, T=512, S=128, L=257.
// FP64 throughout: with random softmax probs the normalized fwd/bwd supports
// become nearly disjoint at mid-t, so lh[t] ~ e^-300 — representable only in
// fp64 (the harness's reference is an fp64 numpy recompute; jax-fp32 is inf).
//
// Per (b, direction) one 64-lane wave runs the length-T scan over L=257 states.
//  lane l owns states s = 4l..4l+3 ; lane 63 additionally owns s = 256.
//  One shfl_up per step: neighbor a3 serves the shift-1 (k=0) and shift-2 (k=1).
//  Even states use the blank row; odd states gather 2 label rows per lane.
// Kernel A (REV=0): alpha pass, stores normalized alpha rows (fp64) to d_ws.
// Kernel B (REV=1,FUSE=1): beta pass; per step fuses lh[t] = sum_s ahat*u*rr
//  (u = pre-p masked shifted sum, so bhat/p needs no division) and accumulates log.
// Kernel R: sums 128 per-batch losses -> d_out[0] (fp32).

#define BB 128
#define CC 512
#define TT 512
#define SS 128
#define LL 257      // 2*S+1
#define LPAD 260    // doubles per row (row stride 2080 B, 16B-aligned)

template<bool REV, bool FUSE>
__global__ __launch_bounds__(64)
void ctc_pass(const float* __restrict__ P, const int* __restrict__ seqg,
              const int* __restrict__ blankp, double* __restrict__ Abuf,
              double* __restrict__ Lbuf)
{
    const int b = blockIdx.x;
    const int l = threadIdx.x;          // 0..63
    const int blank = blankp[0];
    const float* Pb = P + (size_t)b * (CC * TT);
    const int*  sq  = seqg + b * SS;

    // Per-lane label rows and mask2 values (k=1 -> s=4l+1, k=3 -> s=4l+3).
    int r1, r3; double m1, m3;
    if (!REV) {
        r1 = sq[2*l]; r3 = sq[2*l+1];
        m1 = (l == 0) ? 1.0 : ((r1 != sq[2*l-1]) ? 1.0 : 0.0);
        m3 = (r3 != r1) ? 1.0 : 0.0;
    } else {
        // lab_r[s'] = lab[L-1-s']: k=1 -> seq[127-2l], k=3 -> seq[126-2l]
        r1 = sq[SS-1-2*l]; r3 = sq[SS-2-2*l];
        m1 = (l == 0) ? 1.0 : ((r1 != sq[SS-2*l]) ? 1.0 : 0.0);
        m3 = (r3 != r1) ? 1.0 : 0.0;
    }
    const float* pBp = Pb + (size_t)blank * TT;
    const float* p1p = Pb + (size_t)r1   * TT;
    const float* p3p = Pb + (size_t)r3   * TT;
    double* Ab = Abuf + (size_t)b * TT * LPAD;

    // ---- t = 0 (init row; no start-mask) ----
    int pc = REV ? (TT-1) : 0;
    double n0 = (l == 0) ? (double)pBp[pc] : 0.0;   // s=0 (blank)
    double n1 = (l == 0) ? (double)p1p[pc] : 0.0;   // s=1 (first label)
    double c = n0 + n1;
    double traw = 0.0;
    if (FUSE) {
        const double* Ar = Ab + (size_t)pc * LPAD;
        // bhat[s']/p = u*rr with u = 1 at s'=0,1 -> terms ahat[256], ahat[255]
        if (l == 0) traw = Ar[256] + Ar[255];
    }
    #pragma unroll
    for (int off = 32; off; off >>= 1) c += __shfl_xor(c, off);
    if (FUSE) {
        #pragma unroll
        for (int off = 32; off; off >>= 1) traw += __shfl_xor(traw, off);
    }
    double rr = (c > 1e-290) ? (1.0 / c) : 1.0;
    double a0 = n0 * rr, a1 = n1 * rr, a2 = 0.0, a3 = 0.0, a4 = 0.0;
    double lossacc = 0.0;
    if (FUSE) {
        lossacc += log(traw * rr);
    } else {
        *reinterpret_cast<double2*>(Ab + 4*l)     = make_double2(a0, a1);
        *reinterpret_cast<double2*>(Ab + 4*l + 2) = make_double2(0.0, 0.0);
        if (l == 63) Ab[256] = 0.0;
    }

    // ---- t = 1 .. T-1 ----
    for (int t = 1; t < TT; ++t) {
        pc = REV ? (TT-1-t) : t;
        double pB = (double)pBp[pc], p1 = (double)p1p[pc], p3 = (double)p3p[pc];
        double e3u = __shfl_up(a3, 1);
        if (l == 0) e3u = 0.0;
        // shifted sums (u = a + a>>1 + mask2 * a>>2), s = 4l+k
        double u0 = a0 + e3u;               // even s: mask2 = 0
        double u1 = a1 + a0 + m1 * e3u;
        double u2 = a2 + a1;
        double u3 = a3 + a2 + m3 * a1;
        double u4 = a4 + a3;                // s=256, valid on l==63 only
        if (t >= TT - SS) {                 // start = 2t - 767 > 0 iff t >= 384
            int start = 2*t - (2*TT - LL);
            if (4*l   < start) u0 = 0.0;
            if (4*l+1 < start) u1 = 0.0;
            if (4*l+2 < start) u2 = 0.0;
            if (4*l+3 < start) u3 = 0.0;
            // s=256 is never below start (start <= 255)
        }
        double n0v = u0 * pB, n1v = u1 * p1, n2v = u2 * pB, n3v = u3 * p3;
        double n4v = u4 * pB;
        double part = n0v + n1v + n2v + n3v;
        if (l == 63) part += n4v;

        double tr = 0.0;
        if (FUSE) {
            // lh[pc] terms: ahat[256-4l-k, pc] * u_k * rr
            const double* Ar = Ab + (size_t)pc * LPAD;
            tr = Ar[256-4*l] * u0 + Ar[255-4*l] * u1
               + Ar[254-4*l] * u2 + Ar[253-4*l] * u3;
            if (l == 63) tr += Ar[0] * u4;
        }

        double cs = part;
        #pragma unroll
        for (int off = 32; off; off >>= 1) cs += __shfl_xor(cs, off);
        if (FUSE) {
            #pragma unroll
            for (int off = 32; off; off >>= 1) tr += __shfl_xor(tr, off);
        }
        rr = (cs > 1e-290) ? (1.0 / cs) : 1.0;
        a0 = n0v * rr; a1 = n1v * rr; a2 = n2v * rr; a3 = n3v * rr;
        a4 = n4v * rr;

        if (FUSE) {
            lossacc += log(tr * rr);
        } else {
            double* Aw = Ab + (size_t)t * LPAD;
            *reinterpret_cast<double2*>(Aw + 4*l)     = make_double2(a0, a1);
            *reinterpret_cast<double2*>(Aw + 4*l + 2) = make_double2(a2, a3);
            if (l == 63) Aw[256] = a4;
        }
    }

    if (FUSE && l == 0) Lbuf[b] = -lossacc;
}

__global__ __launch_bounds__(128)
void ctc_reduce(const double* __restrict__ Lbuf, float* __restrict__ out)
{
    const int l = threadIdx.x;           // 128 threads = 2 waves
    double v = Lbuf[l];
    #pragma unroll
    for (int off = 32; off; off >>= 1) v += __shfl_xor(v, off);
    __shared__ double w[2];
    if ((l & 63) == 0) w[l >> 6] = v;
    __syncthreads();
    if (l == 0) out[0] = (float)(w[0] + w[1]);
}

extern "C" void kernel_launch(void* const* d_in, const int* in_sizes, int n_in,
                              void* d_out, int out_size, void* d_ws, size_t ws_size,
                              hipStream_t stream)
{
    const float* P     = (const float*)d_in[0];   // params (B,C,T) fp32
    const int*   seq   = (const int*)  d_in[1];   // (B,S) int32
    // d_in[2] = lengths (unused by the reference computation)
    const int*   blank = (const int*)  d_in[3];   // scalar int

    // Workspace layout: alpha buffer [B][T][LPAD] fp64, then per-batch losses.
    const size_t abytes = (size_t)BB * TT * LPAD * sizeof(double);  // ~136.3 MB
    double* A  = (double*)d_ws;
    double* Lb = (double*)((char*)d_ws + abytes);
    (void)ws_size; (void)in_sizes; (void)n_in; (void)out_size;

    ctc_pass<false, false><<<BB, 64, 0, stream>>>(P, seq, blank, A, nullptr);
    ctc_pass<true,  true ><<<BB, 64, 0, stream>>>(P, seq, blank, A, Lb);
    ctc_reduce<<<1, 128, 0, stream>>>(Lb, (float*)d_out);
}

// Round 3
// 234.293 us; speedup vs baseline: 2.9979x; 2.9979x over previous
//
#include <hip/hip_runtime.h>
#include <math.h>

// CTC loss (per-step-normalized fwd/bwd), B=128, C=512, T=512, S=128, L=257.
// Round-3 restructure: all cross-lane via DPP (no LDS), deferred normalization
// (no divides/logs in the scans; scale kept in-band with exact 2^-e rescale
// folded into p, e from the previous step's sum — cancels in v/S), register
// prefetch for p (depth 8) and alpha-row fragments (depth 4).
//  lane l owns states s = 4l..4l+3 ; lane 63 additionally owns s = 256.
// K1 alpha: stores RAW rows + row sums Sa[t].   K2 beta(fused): stores per
// step num = (sum_s v_a * u_b) * 2^-e and Sb.   K3: loss_b = sum_t [log Sa +
// log Sb - log num] (parallel logs).   K4: sum over b -> f32 out.

#define BB 128
#define CC 512
#define TT 512
#define SS 128
#define LL 257
#define LPAD 260    // doubles per row (2080 B, 16B aligned)

// ---- DPP helpers (gfx9-family controls, valid on gfx950) ----
template<int CTRL>
__device__ __forceinline__ double dpp0_f64(double x) {
    int2 v = __builtin_bit_cast(int2, x);
    int2 r;
    r.x = __builtin_amdgcn_update_dpp(0, v.x, CTRL, 0xF, 0xF, true);
    r.y = __builtin_amdgcn_update_dpp(0, v.y, CTRL, 0xF, 0xF, true);
    return __builtin_bit_cast(double, r);
}
// shfl_up by 1 across the full wave, zero-fill at lane 0 (WAVE_SHR1 = 0x138)
__device__ __forceinline__ double shfl_up1_f64(double x) { return dpp0_f64<0x138>(x); }
// full 64-lane sum; result valid in lane 63 (canonical gfx9 DPP reduction)
__device__ __forceinline__ double wave_sum63(double x) {
    x += dpp0_f64<0x111>(x);  // row_shr:1
    x += dpp0_f64<0x112>(x);  // row_shr:2
    x += dpp0_f64<0x114>(x);  // row_shr:4
    x += dpp0_f64<0x118>(x);  // row_shr:8
    x += dpp0_f64<0x142>(x);  // row_bcast:15
    x += dpp0_f64<0x143>(x);  // row_bcast:31
    return x;
}
__device__ __forceinline__ double readlane63_f64(double x) {
    int2 v = __builtin_bit_cast(int2, x);
    int2 r;
    r.x = __builtin_amdgcn_readlane(v.x, 63);
    r.y = __builtin_amdgcn_readlane(v.y, 63);
    return __builtin_bit_cast(double, r);
}

template<bool FUSE>
__global__ __launch_bounds__(64)
void ctc_scan(const float* __restrict__ P, const int* __restrict__ seqg,
              const int* __restrict__ blankp, double* __restrict__ Abuf,
              double* __restrict__ Sa, double* __restrict__ NumSb)
{
    const int b = blockIdx.x;
    const int l = threadIdx.x;          // 0..63
    const bool is63 = (l == 63);
    const int blank = blankp[0];
    const float* Pb = P + (size_t)b * (CC * TT);
    const int*  sq  = seqg + b * SS;

    // per-lane label rows + mask2 (k=1 -> s=4l+1, k=3 -> s=4l+3)
    int r1, r3; double m1, m3;
    if (!FUSE) {
        r1 = sq[2*l]; r3 = sq[2*l+1];
        int ip = (l == 0) ? 0 : (2*l - 1);          // avoid OOB for l==0
        m1 = (l == 0) ? 1.0 : ((r1 != sq[ip]) ? 1.0 : 0.0);
        m3 = (r3 != r1) ? 1.0 : 0.0;
    } else {
        r1 = sq[SS-1-2*l]; r3 = sq[SS-2-2*l];
        int ip = (l == 0) ? 0 : (SS - 2*l);          // avoid OOB for l==0
        m1 = (l == 0) ? 1.0 : ((r1 != sq[ip]) ? 1.0 : 0.0);
        m3 = (r3 != r1) ? 1.0 : 0.0;
    }
    const float* pBp = Pb + (size_t)blank * TT;
    const float* p1p = Pb + (size_t)r1   * TT;
    const float* p3p = Pb + (size_t)r3   * TT;
    double* Ab = Abuf + (size_t)b * TT * LPAD;

    // start-mask thresholds: state s masked at step i iff i >= (s+769)>>1
    const int tm0 = (4*l     + 769) >> 1;
    const int tm1 = (4*l + 1 + 769) >> 1;
    const int tm2 = (4*l + 2 + 769) >> 1;
    const int tm3 = (4*l + 3 + 769) >> 1;

    // p prefetch (depth 8, rotating register buffer)
    float pbB[8], pb1[8], pb3[8];
    #pragma unroll
    for (int j = 0; j < 8; ++j) {
        int pc = FUSE ? (TT-1-j) : j;
        pbB[j] = pBp[pc]; pb1[j] = p1p[pc]; pb3[j] = p3p[pc];
    }
    // alpha-row fragment prefetch (FUSE only, depth 4):
    // lane l needs Ar[252-4l .. 256-4l]; element m=0 used only on lane 63.
    double arb[4][5];
    if (FUSE) {
        #pragma unroll
        for (int j = 0; j < 4; ++j) {
            const double* Ar = Ab + (size_t)(TT-1-j) * LPAD + (252 - 4*l);
            #pragma unroll
            for (int m = 0; m < 5; ++m) arb[j][m] = Ar[m];
        }
    }

    double a0=0, a1=0, a2=0, a3=0, a4=0;
    double sc = 1.0;           // 2^-eCur, folded into p this step
    int eCur = 0;
    const double u0init = (l == 0) ? 1.0 : 0.0;

    for (int i0 = 0; i0 < TT; i0 += 8) {
        #pragma unroll
        for (int j = 0; j < 8; ++j) {
            const int i = i0 + j;
            double u0, u1, u2, u3, u4;
            if (j == 0 && i0 == 0) {
                // init row: v0 = p_ext at s=0,1 (u=1 there), no mask
                u0 = u0init; u1 = u0init; u2 = 0.0; u3 = 0.0; u4 = 0.0;
            } else {
                double e3u = shfl_up1_f64(a3);       // a3 from lane l-1, 0 at l=0
                u0 = a0 + e3u;
                u1 = (a1 + a0) + m1 * e3u;
                u2 = a2 + a1;
                u3 = (a3 + a2) + m3 * a1;
                u4 = a4 + a3;                         // s=256 (valid on l63)
                if (i >= TT - SS) {                   // start-mask active
                    if (i >= tm0) u0 = 0.0;
                    if (i >= tm1) u1 = 0.0;
                    if (i >= tm2) u2 = 0.0;
                    if (i >= tm3) u3 = 0.0;
                }
            }
            double pBs = (double)pbB[j] * sc;
            double p1s = (double)pb1[j] * sc;
            double p3s = (double)pb3[j] * sc;
            double n0 = u0*pBs, n1 = u1*p1s, n2 = u2*pBs, n3 = u3*p3s, n4 = u4*pBs;
            double part = (n0 + n1) + (n2 + n3);
            if (is63) part += n4;
            double S = wave_sum63(part);              // full sum in lane 63

            if (FUSE) {
                const int sl = j & 3;
                // lh terms: sum_s v_a[L-1-s'] * u[s']  (maps to m=4..1, +m=0 on l63)
                double trp = arb[sl][4]*u0 + arb[sl][3]*u1
                           + arb[sl][2]*u2 + arb[sl][1]*u3;
                if (is63) trp += arb[sl][0]*u4;
                double TR = wave_sum63(trp);
                if (is63) {
                    double2 w; w.x = TR * sc; w.y = S;   // num = tr_raw * 2^-eCur
                    *reinterpret_cast<double2*>(NumSb + 2*((size_t)b*TT + i)) = w;
                }
                // reload slot with row for step i+4 (clamped; tail loads unused)
                int ipf = (i + 4 < TT) ? (i + 4) : (TT - 1);
                const double* Ar = Ab + (size_t)(TT-1-ipf) * LPAD + (252 - 4*l);
                #pragma unroll
                for (int m = 0; m < 5; ++m) arb[sl][m] = Ar[m];
            } else {
                double* Aw = Ab + (size_t)i * LPAD;
                double2 w01; w01.x = n0; w01.y = n1;
                double2 w23; w23.x = n2; w23.y = n3;
                *reinterpret_cast<double2*>(Aw + 4*l)     = w01;
                *reinterpret_cast<double2*>(Aw + 4*l + 2) = w23;
                if (is63) { Aw[256] = n4; Sa[(size_t)b*TT + i] = S; }
            }

            // next-step exact power-2 rescale from this step's sum (uniform)
            double Su = readlane63_f64(S);
            int hi = __double2hiint(Su);
            int ex = (hi >> 20) & 0x7FF;
            ex = (ex == 0) ? 1023 : ex;               // S zero/denormal -> sc=1
            ex = (ex > 1800) ? 1800 : ex;
            eCur = ex - 1023;
            sc = __hiloint2double((1023 - eCur) << 20, 0);   // exact 2^-eCur

            a0 = n0; a1 = n1; a2 = n2; a3 = n3; a4 = n4;

            // p prefetch for step i+8 (clamped; tail loads unused)
            int inx = (i + 8 < TT) ? (i + 8) : (TT - 1);
            int pcn = FUSE ? (TT-1-inx) : inx;
            pbB[j] = pBp[pcn]; pb1[j] = p1p[pcn]; pb3[j] = p3p[pcn];
        }
    }
}

__global__ __launch_bounds__(64)
void ctc_logsum(const double* __restrict__ Sa, const double* __restrict__ NumSb,
                double* __restrict__ Lb)
{
    const int b = blockIdx.x, l = threadIdx.x;
    double acc = 0.0;
    #pragma unroll
    for (int j = 0; j < 8; ++j) {
        int t = j*64 + l;
        double sa = Sa[(size_t)b*TT + t];
        double2 ns = *reinterpret_cast<const double2*>(NumSb + 2*((size_t)b*TT + t));
        // loss_b = -sum_t log lh_t ;  log lh_t = log num - log Sa - log Sb
        acc += log(sa) + log(ns.y) - log(ns.x);
    }
    double tot = wave_sum63(acc);
    if (l == 63) Lb[b] = tot;
}

__global__ __launch_bounds__(128)
void ctc_final(const double* __restrict__ Lb, float* __restrict__ out)
{
    const int l = threadIdx.x;           // 128 threads = 2 waves
    double v = Lb[l];
    double s = wave_sum63(v);
    __shared__ double w[2];
    if ((l & 63) == 63) w[l >> 6] = s;
    __syncthreads();
    if (l == 0) out[0] = (float)(w[0] + w[1]);
}

extern "C" void kernel_launch(void* const* d_in, const int* in_sizes, int n_in,
                              void* d_out, int out_size, void* d_ws, size_t ws_size,
                              hipStream_t stream)
{
    const float* P     = (const float*)d_in[0];   // params (B,C,T) fp32
    const int*   seq   = (const int*)  d_in[1];   // (B,S) int32
    // d_in[2] = lengths (unused by the reference computation)
    const int*   blank = (const int*)  d_in[3];   // scalar int

    double* A     = (double*)d_ws;                           // B*T*LPAD   (~136.3 MB)
    double* Sa    = A    + (size_t)BB*TT*LPAD;                // B*T        (0.5 MB)
    double* NumSb = Sa   + (size_t)BB*TT;                     // B*T*2      (1 MB)
    double* Lb    = NumSb + (size_t)BB*TT*2;                  // B          (1 KB)
    (void)ws_size; (void)in_sizes; (void)n_in; (void)out_size;

    ctc_scan<false><<<BB, 64, 0, stream>>>(P, seq, blank, A, Sa, NumSb);
    ctc_scan<true ><<<BB, 64, 0, stream>>>(P, seq, blank, A, Sa, NumSb);
    ctc_logsum<<<BB, 64, 0, stream>>>(Sa, NumSb, Lb);
    ctc_final<<<1, 128, 0, stream>>>(Lb, (float*)d_out);
}

// Round 4
// 176.169 us; speedup vs baseline: 3.9871x; 1.3299x over previous
//
#include <hip/hip_runtime.h>
#include <math.h>

// CTC loss (per-step-normalized fwd/bwd), B=128, C=512, T=512, S=128, L=257.
// Round-4: reduction OFF the recursion chain. Scans rescale by 2^-e only every
// 8 steps (lagged full butterfly); per-step sums are stored as 8:1 DPP-reduced
// partials and finished in a parallel combine kernel:
//   lh_t = h_i * D'_i / (S_t * R_i),  D'_i = sum_s w_a[s,t] * U_i[s]
// with w_a raw alpha rows (sum S_t), U_i raw pre-p beta shifts (x sums R_i),
// h_i the beta scale applied at step i (folded into stored D). A feedback-
// tracked exponent boost 2^G keeps stored D in fp64 range even when lh is
// not representable (G stored per step; term = log D - G*ln2 - log(S*R)).

#define BB 128
#define CC 512
#define TT 512
#define SS 128
#define LL 257
#define LPAD 260    // doubles per row (2080 B, 16B aligned)

// ---- DPP helpers (gfx9-family controls; validated on gfx950 in round 3) ----
template<int CTRL>
__device__ __forceinline__ double dpp0_f64(double x) {
    int2 v = __builtin_bit_cast(int2, x);
    int2 r;
    r.x = __builtin_amdgcn_update_dpp(0, v.x, CTRL, 0xF, 0xF, true);
    r.y = __builtin_amdgcn_update_dpp(0, v.y, CTRL, 0xF, 0xF, true);
    return __builtin_bit_cast(double, r);
}
// shift whole wave down by 1 lane (lane0 gets 0): WAVE_SHR1
__device__ __forceinline__ double shfl_up1_f64(double x){ return dpp0_f64<0x138>(x); }
// 3-stage inclusive scan: lanes l%8==7 hold their 8-group sum
__device__ __forceinline__ double red8(double x){
    x += dpp0_f64<0x111>(x);  // row_shr:1
    x += dpp0_f64<0x112>(x);  // row_shr:2
    x += dpp0_f64<0x114>(x);  // row_shr:4
    return x;
}
// finish a red8 state to a full 64-lane sum in lane 63
__device__ __forceinline__ double tail3(double x){
    x += dpp0_f64<0x118>(x);  // row_shr:8
    x += dpp0_f64<0x142>(x);  // row_bcast:15
    x += dpp0_f64<0x143>(x);  // row_bcast:31
    return x;
}
__device__ __forceinline__ double readlane63_f64(double x){
    int2 v = __builtin_bit_cast(int2, x);
    int2 r; r.x = __builtin_amdgcn_readlane(v.x, 63);
            r.y = __builtin_amdgcn_readlane(v.y, 63);
    return __builtin_bit_cast(double, r);
}
__device__ __forceinline__ double pow2i(int e){   // |e| <= 1022, exact
    return __hiloint2double((1023 + e) << 20, 0);
}

// =========================== alpha scan ===========================
__global__ __launch_bounds__(64)
void ctc_alpha(const float* __restrict__ P, const int* __restrict__ seqg,
               const int* __restrict__ blankp, double* __restrict__ Abuf)
{
    const int b = blockIdx.x, l = threadIdx.x;
    const bool is63 = (l == 63);
    const int blank = blankp[0];
    const float* Pb = P + (size_t)b * (CC*TT);
    const int* sq = seqg + b*SS;

    const int r1 = sq[2*l], r3 = sq[2*l+1];
    const int ip = (l==0) ? 0 : (2*l-1);
    const double m1 = (l==0) ? 1.0 : ((r1 != sq[ip]) ? 1.0 : 0.0);
    const double m3 = (r3 != r1) ? 1.0 : 0.0;
    const float* pBp = Pb + (size_t)blank*TT;
    const float* p1p = Pb + (size_t)r1*TT;
    const float* p3p = Pb + (size_t)r3*TT;
    double* Aw = Abuf + (size_t)b*TT*LPAD;

    // start-mask thresholds: state s masked at step i iff i >= (s+769)>>1
    const int tm0=(4*l+769)>>1, tm1=(4*l+770)>>1, tm2=(4*l+771)>>1, tm3=(4*l+772)>>1;

    float pbB[8], pb1[8], pb3[8];
    #pragma unroll
    for (int j=0;j<8;++j){ pbB[j]=pBp[j]; pb1[j]=p1p[j]; pb3[j]=p3p[j]; }

    double a0=0,a1=0,a2=0,a3=0,a4=0;
    double scNext = 1.0, Sfull = 0.0;
    const double u0i = (l==0) ? 1.0 : 0.0;

#define ASTEP(i, j, FIRSTF, MASKF)                                          \
  {                                                                         \
    double u0,u1,u2,u3,u4;                                                  \
    if (FIRSTF) { u0=u0i; u1=u0i; u2=0.0; u3=0.0; u4=0.0; }                 \
    else {                                                                  \
      double e3u = shfl_up1_f64(a3);                                        \
      u0 = a0 + e3u; u1 = (a1+a0) + m1*e3u; u2 = a2+a1;                     \
      u3 = (a3+a2) + m3*a1; u4 = a4+a3;                                     \
      if (MASKF) {                                                          \
        if ((i) >= tm0) u0 = 0.0;                                           \
        if ((i) >= tm1) u1 = 0.0;                                           \
        if ((i) >= tm2) u2 = 0.0;                                           \
        if ((i) >= tm3) u3 = 0.0;                                           \
      }                                                                     \
    }                                                                       \
    double pB=(double)pbB[j], pq=(double)pb1[j], pr=(double)pb3[j];         \
    if ((j)==0) { pB*=scNext; pq*=scNext; pr*=scNext; }                     \
    double n0=u0*pB, n1=u1*pq, n2=u2*pB, n3=u3*pr, n4=u4*pB;                \
    *reinterpret_cast<double2*>(Aw + 4*l)   = make_double2(n0,n1);          \
    *reinterpret_cast<double2*>(Aw + 4*l+2) = make_double2(n2,n3);          \
    if (is63) Aw[256] = n4;                                                 \
    Aw += LPAD;                                                             \
    if ((j)==5) {                                                           \
      double part=(n0+n1)+(n2+n3); if (is63) part+=n4;                      \
      Sfull = tail3(red8(part));                                            \
    }                                                                       \
    if ((j)==7) {                                                           \
      double Su = readlane63_f64(Sfull);                                    \
      int ex = (__double2hiint(Su)>>20) & 0x7FF;                            \
      int e = (ex==0) ? -512 : (ex-1023);                                   \
      e = e < -900 ? -900 : (e > 900 ? 900 : e);                            \
      scNext = pow2i(-e);                                                   \
    }                                                                       \
    a0=n0; a1=n1; a2=n2; a3=n3; a4=n4;                                      \
    int inx = ((i)+8 < TT) ? (i)+8 : TT-1;                                  \
    pbB[j]=pBp[inx]; pb1[j]=p1p[inx]; pb3[j]=p3p[inx];                      \
  }

    // group 0 peeled (init row at i=0; no mask possible before i=384)
    ASTEP(0,0,true,false)  ASTEP(1,1,false,false) ASTEP(2,2,false,false)
    ASTEP(3,3,false,false) ASTEP(4,4,false,false) ASTEP(5,5,false,false)
    ASTEP(6,6,false,false) ASTEP(7,7,false,false)
    for (int i0=8; i0<TT-SS; i0+=8) {
        #pragma unroll
        for (int j=0;j<8;++j) ASTEP(i0+j, j, false, false)
    }
    for (int i0=TT-SS; i0<TT; i0+=8) {
        #pragma unroll
        for (int j=0;j<8;++j) ASTEP(i0+j, j, false, true)
    }
#undef ASTEP
}

// =========================== beta scan (fused dot) ===========================
__global__ __launch_bounds__(64)
void ctc_beta(const float* __restrict__ P, const int* __restrict__ seqg,
              const int* __restrict__ blankp, const double* __restrict__ Abuf,
              double* __restrict__ D8, double* __restrict__ R8,
              double* __restrict__ S8, int* __restrict__ Gp)
{
    const int b = blockIdx.x, l = threadIdx.x;
    const bool is63 = (l == 63);
    const bool is7  = ((l & 7) == 7);
    const int blank = blankp[0];
    const float* Pb = P + (size_t)b * (CC*TT);
    const int* sq = seqg + b*SS;

    // reversed labels: lab_r[s'] = lab[L-1-s']
    const int r1 = sq[SS-1-2*l], r3 = sq[SS-2-2*l];
    const int ip = (l==0) ? 0 : (SS-2*l);
    const double m1 = (l==0) ? 1.0 : ((r1 != sq[ip]) ? 1.0 : 0.0);
    const double m3 = (r3 != r1) ? 1.0 : 0.0;
    const float* pBp = Pb + (size_t)blank*TT;
    const float* p1p = Pb + (size_t)r1*TT;
    const float* p3p = Pb + (size_t)r3*TT;
    const double* Ab = Abuf + (size_t)b*TT*LPAD;

    const int tm0=(4*l+769)>>1, tm1=(4*l+770)>>1, tm2=(4*l+771)>>1, tm3=(4*l+772)>>1;

    float pbB[8], pb1[8], pb3[8];
    #pragma unroll
    for (int j=0;j<8;++j){ int pc=TT-1-j; pbB[j]=pBp[pc]; pb1[j]=p1p[pc]; pb3[j]=p3p[pc]; }

    // alpha-row fragments (lane l holds row[252-4l .. 256-4l]), depth 4
    double arb[4][5];
    #pragma unroll
    for (int j=0;j<4;++j){
        const double* Ar = Ab + (size_t)(TT-1-j)*LPAD + (252-4*l);
        double2 q01 = *reinterpret_cast<const double2*>(Ar);
        double2 q23 = *reinterpret_cast<const double2*>(Ar+2);
        arb[j][0]=q01.x; arb[j][1]=q01.y; arb[j][2]=q23.x; arb[j][3]=q23.y;
        arb[j][4]=Ar[4];
    }

    double* dD = D8 + (size_t)b*TT*8 + (l>>3);
    double* dR = R8 + (size_t)b*TT*8 + (l>>3);
    double* dS = S8 + (size_t)b*TT*8 + (l>>3);
    int*    gq = Gp + b*TT;

    double a0=0,a1=0,a2=0,a3=0,a4=0;
    double scNext = 1.0, gScale = 1.0, gScaleNext = 1.0;
    int G = 0, Gnext = 0;
    double Rfull = 0.0, Dfull = 0.0;
    const double u0i = (l==0) ? 1.0 : 0.0;

#define BSTEP(i, j, FIRSTF, MASKF)                                          \
  {                                                                         \
    double u0,u1,u2,u3,u4;                                                  \
    if (FIRSTF) { u0=u0i; u1=u0i; u2=0.0; u3=0.0; u4=0.0; }                 \
    else {                                                                  \
      double e3u = shfl_up1_f64(a3);                                        \
      u0 = a0 + e3u; u1 = (a1+a0) + m1*e3u; u2 = a2+a1;                     \
      u3 = (a3+a2) + m3*a1; u4 = a4+a3;                                     \
      if (MASKF) {                                                          \
        if ((i) >= tm0) u0 = 0.0;                                           \
        if ((i) >= tm1) u1 = 0.0;                                           \
        if ((i) >= tm2) u2 = 0.0;                                           \
        if ((i) >= tm3) u3 = 0.0;                                           \
      }                                                                     \
    }                                                                       \
    const int sl = (j)&3;                                                   \
    double trp = arb[sl][4]*u0 + arb[sl][3]*u1                              \
               + arb[sl][2]*u2 + arb[sl][1]*u3;                             \
    if (is63) trp += arb[sl][0]*u4;                                         \
    double sap = (arb[sl][1]+arb[sl][2]) + (arb[sl][3]+arb[sl][4]);         \
    if (is63) sap += arb[sl][0];                                            \
    { int ipf = ((i)+4 < TT) ? (i)+4 : TT-1;                                \
      const double* Ar = Ab + (size_t)(TT-1-ipf)*LPAD + (252-4*l);          \
      double2 q01 = *reinterpret_cast<const double2*>(Ar);                  \
      double2 q23 = *reinterpret_cast<const double2*>(Ar+2);                \
      arb[sl][0]=q01.x; arb[sl][1]=q01.y; arb[sl][2]=q23.x;                 \
      arb[sl][3]=q23.y; arb[sl][4]=Ar[4]; }                                 \
    if ((j)==0) { G = Gnext; gScale = gScaleNext; }                         \
    double pB=(double)pbB[j], pq=(double)pb1[j], pr=(double)pb3[j];         \
    if ((j)==0) { pB*=scNext; pq*=scNext; pr*=scNext; }                     \
    double n0=u0*pB, n1=u1*pq, n2=u2*pB, n3=u3*pr, n4=u4*pB;                \
    double rp=(n0+n1)+(n2+n3); if (is63) rp+=n4;                            \
    double Ds = red8(trp) * gScale;                                         \
    if ((j)==0) Ds *= scNext;                                               \
    double Rs = red8(rp);                                                   \
    double Ss = red8(sap);                                                  \
    if (is7) { dD[0]=Ds; dR[0]=Rs; dS[0]=Ss; }                              \
    if (l==0) gq[i] = G;                                                    \
    dD+=8; dR+=8; dS+=8;                                                    \
    if ((j)==5) { Rfull = tail3(Rs); Dfull = tail3(Ds); }                   \
    if ((j)==7) {                                                           \
      double Ru = readlane63_f64(Rfull);                                    \
      int ex = (__double2hiint(Ru)>>20) & 0x7FF;                            \
      int e = (ex==0) ? -512 : (ex-1023);                                   \
      e = e < -900 ? -900 : (e > 900 ? 900 : e);                            \
      scNext = pow2i(-e);                                                   \
      double Du = readlane63_f64(Dfull);                                    \
      int dex = (__double2hiint(Du)>>20) & 0x7FF;                           \
      int adj = (dex==0) ? 512 : (1023-dex);                                \
      Gnext = G + adj;                                                      \
      Gnext = Gnext < -60 ? -60 : (Gnext > 1000 ? 1000 : Gnext);            \
      gScaleNext = pow2i(Gnext);                                            \
    }                                                                       \
    a0=n0; a1=n1; a2=n2; a3=n3; a4=n4;                                      \
    int inx = ((i)+8 < TT) ? (i)+8 : TT-1;                                  \
    int pcn = TT-1-inx;                                                     \
    pbB[j]=pBp[pcn]; pb1[j]=p1p[pcn]; pb3[j]=p3p[pcn];                      \
  }

    BSTEP(0,0,true,false)  BSTEP(1,1,false,false) BSTEP(2,2,false,false)
    BSTEP(3,3,false,false) BSTEP(4,4,false,false) BSTEP(5,5,false,false)
    BSTEP(6,6,false,false) BSTEP(7,7,false,false)
    for (int i0=8; i0<TT-SS; i0+=8) {
        #pragma unroll
        for (int j=0;j<8;++j) BSTEP(i0+j, j, false, false)
    }
    for (int i0=TT-SS; i0<TT; i0+=8) {
        #pragma unroll
        for (int j=0;j<8;++j) BSTEP(i0+j, j, false, true)
    }
#undef BSTEP
}

// =========================== combine (parallel logs) ===========================
__global__ __launch_bounds__(64)
void ctc_combine(const double* __restrict__ D8, const double* __restrict__ R8,
                 const double* __restrict__ S8, const int* __restrict__ Gp,
                 double* __restrict__ Lq)
{
    const int b = blockIdx.x, q = blockIdx.y, l = threadIdx.x;
    const size_t base = ((size_t)b*TT + q*64)*8;   // doubles; 8 per step
    const int ibase = q*64;
    double acc = 0.0;
    #pragma unroll
    for (int it=0; it<8; ++it) {
        size_t o = base + (size_t)it*64 + l;       // lane: i_local=l>>3, slot=l&7
        double d = red8(D8[o]);
        double r = red8(R8[o]);
        double s = red8(S8[o]);
        int Gi = Gp[b*TT + ibase + it*8 + (l>>3)];
        double dd = fmax(d, 1e-300);
        double sr = fmax(s*r, 1e-300);
        double term = log(dd) - (double)Gi*M_LN2 - log(sr);  // log lh_t
        acc += ((l&7)==7) ? term : 0.0;
    }
    double tot = tail3(red8(acc));
    if (l == 63) Lq[(size_t)b*8 + q] = tot;
}

__global__ __launch_bounds__(256)
void ctc_final(const double* __restrict__ Lq, float* __restrict__ out)
{
    const int t = threadIdx.x;   // 256 threads = 4 waves; 1024 inputs
    double v = Lq[t] + Lq[t+256] + Lq[t+512] + Lq[t+768];
    double s = tail3(red8(v));
    __shared__ double w[4];
    if ((t & 63) == 63) w[t>>6] = s;
    __syncthreads();
    if (t == 0) out[0] = (float)(-(w[0]+w[1]+w[2]+w[3]));
}

extern "C" void kernel_launch(void* const* d_in, const int* in_sizes, int n_in,
                              void* d_out, int out_size, void* d_ws, size_t ws_size,
                              hipStream_t stream)
{
    const float* P     = (const float*)d_in[0];   // params (B,C,T) fp32
    const int*   seq   = (const int*)  d_in[1];   // (B,S) int32
    // d_in[2] = lengths (unused by the reference computation)
    const int*   blank = (const int*)  d_in[3];   // scalar int

    // ws layout (doubles): A rows | D8 | R8 | S8 | Gp(int) | Lq   (~149.2 MB)
    double* A  = (double*)d_ws;
    double* D8 = A  + (size_t)BB*TT*LPAD;         // 17,039,360 doubles
    double* R8 = D8 + (size_t)BB*TT*8;            // 524,288 doubles each
    double* S8 = R8 + (size_t)BB*TT*8;
    int*    Gp = (int*)(S8 + (size_t)BB*TT*8);    // 262,144 ints
    double* Lq = (double*)((char*)Gp + (size_t)BB*TT*sizeof(int));  // 1024 doubles
    (void)ws_size; (void)in_sizes; (void)n_in; (void)out_size;

    ctc_alpha<<<BB, 64, 0, stream>>>(P, seq, blank, A);
    ctc_beta <<<BB, 64, 0, stream>>>(P, seq, blank, A, D8, R8, S8, Gp);
    ctc_combine<<<dim3(BB, 8), 64, 0, stream>>>(D8, R8, S8, Gp, Lq);
    ctc_final<<<1, 256, 0, stream>>>(Lq, (float*)d_out);
}

// Round 5
// 134.737 us; speedup vs baseline: 5.2131x; 1.3075x over previous
//
#include <hip/hip_runtime.h>
#include <math.h>

// CTC loss (per-step-normalized fwd/bwd), B=128, C=512, T=512, S=128, L=257.
// Round-5: alpha and beta scans are both "row-storing" scans (no fused dot) and
// run CONCURRENTLY in one dispatch (256 blocks; block<128 = alpha, else beta).
// Identity used by the parallel combine pass (per original time t, i = T-1-t):
//   lh_t = sigma_i * (sum_s w_a[256-s', t] * U_i[s']) / (S_t * R_i)
//   U_i  = masked shift of stored beta row i-1 (same DPP shift as the scan)
//   S_t  = sum_s w_a[s,t],  R_i = sum_s w_b[s,i]  (from the loaded rows)
//   sigma_i = 2^-e_g, the group rescale folded into p at steps i = 8g (stored).
// All embedded scale factors cancel; per-step normalization is reproduced
// exactly. Combine is BW-bound and fully parallel (8192 waves).

#define BB 128
#define CC 512
#define TT 512
#define SS 128
#define LL 257
#define LPAD 260    // doubles per row (2080 B, 16B aligned)

// ---- DPP helpers (gfx9-family controls; validated on gfx950 rounds 3-4) ----
template<int CTRL>
__device__ __forceinline__ double dpp0_f64(double x) {
    int2 v = __builtin_bit_cast(int2, x);
    int2 r;
    r.x = __builtin_amdgcn_update_dpp(0, v.x, CTRL, 0xF, 0xF, true);
    r.y = __builtin_amdgcn_update_dpp(0, v.y, CTRL, 0xF, 0xF, true);
    return __builtin_bit_cast(double, r);
}
__device__ __forceinline__ double shfl_up1_f64(double x){ return dpp0_f64<0x138>(x); }
__device__ __forceinline__ double red8(double x){
    x += dpp0_f64<0x111>(x);  // row_shr:1
    x += dpp0_f64<0x112>(x);  // row_shr:2
    x += dpp0_f64<0x114>(x);  // row_shr:4
    return x;
}
__device__ __forceinline__ double tail3(double x){   // full 64-lane sum -> lane 63
    x += dpp0_f64<0x118>(x);  // row_shr:8
    x += dpp0_f64<0x142>(x);  // row_bcast:15
    x += dpp0_f64<0x143>(x);  // row_bcast:31
    return x;
}
__device__ __forceinline__ double full64(double x){ return tail3(red8(x)); }
__device__ __forceinline__ double readlane63_f64(double x){
    int2 v = __builtin_bit_cast(int2, x);
    int2 r; r.x = __builtin_amdgcn_readlane(v.x, 63);
            r.y = __builtin_amdgcn_readlane(v.y, 63);
    return __builtin_bit_cast(double, r);
}
__device__ __forceinline__ double pow2i(int e){   // |e| <= 1022, exact
    return __hiloint2double((1023 + e) << 20, 0);
}

// =========================== row-storing scan (both roles) ===========================
template<bool REV>
__device__ __forceinline__ void scan_body(
    int b, int l, const float* __restrict__ P, const int* __restrict__ seqg,
    int blank, double* __restrict__ W, int* __restrict__ Eb)
{
    const bool is63 = (l == 63);
    const float* Pb = P + (size_t)b * (CC*TT);
    const int* sq = seqg + b*SS;

    int r1, r3; double m1, m3;
    if (!REV) {
        r1 = sq[2*l]; r3 = sq[2*l+1];
        int ip = (l==0) ? 0 : (2*l-1);
        m1 = (l==0) ? 1.0 : ((r1 != sq[ip]) ? 1.0 : 0.0);
        m3 = (r3 != r1) ? 1.0 : 0.0;
    } else {
        r1 = sq[SS-1-2*l]; r3 = sq[SS-2-2*l];
        int ip = (l==0) ? 0 : (SS-2*l);
        m1 = (l==0) ? 1.0 : ((r1 != sq[ip]) ? 1.0 : 0.0);
        m3 = (r3 != r1) ? 1.0 : 0.0;
    }
    const float* pBp = Pb + (size_t)blank*TT;
    const float* p1p = Pb + (size_t)r1*TT;
    const float* p3p = Pb + (size_t)r3*TT;
    double* Ww = W + (size_t)b*TT*LPAD;
    int* EbB = Eb + b*64;

    // start-mask thresholds: state s masked at step i iff i >= (s+769)>>1
    const int tm0=(4*l+769)>>1, tm1=(4*l+770)>>1, tm2=(4*l+771)>>1, tm3=(4*l+772)>>1;

    float pbB[8], pb1[8], pb3[8];
    #pragma unroll
    for (int j=0;j<8;++j){
        int pc = REV ? (TT-1-j) : j;
        pbB[j]=pBp[pc]; pb1[j]=p1p[pc]; pb3[j]=p3p[pc];
    }

    double a0=0,a1=0,a2=0,a3=0,a4=0;
    double scNext = 1.0, Sfull = 0.0;
    const double u0i = (l==0) ? 1.0 : 0.0;

#define STEP(i, j, FIRSTF, MASKF)                                           \
  {                                                                         \
    double u0,u1,u2,u3,u4;                                                  \
    if (FIRSTF) { u0=u0i; u1=u0i; u2=0.0; u3=0.0; u4=0.0; }                 \
    else {                                                                  \
      double e3u = shfl_up1_f64(a3);                                        \
      u0 = a0 + e3u; u1 = (a1+a0) + m1*e3u; u2 = a2+a1;                     \
      u3 = (a3+a2) + m3*a1; u4 = a4+a3;                                     \
      if (MASKF) {                                                          \
        if ((i) >= tm0) u0 = 0.0;                                           \
        if ((i) >= tm1) u1 = 0.0;                                           \
        if ((i) >= tm2) u2 = 0.0;                                           \
        if ((i) >= tm3) u3 = 0.0;                                           \
      }                                                                     \
    }                                                                       \
    double pB=(double)pbB[j], pq=(double)pb1[j], pr=(double)pb3[j];         \
    if ((j)==0) { pB*=scNext; pq*=scNext; pr*=scNext; }                     \
    double n0=u0*pB, n1=u1*pq, n2=u2*pB, n3=u3*pr, n4=u4*pB;                \
    *reinterpret_cast<double2*>(Ww + 4*l)   = make_double2(n0,n1);          \
    *reinterpret_cast<double2*>(Ww + 4*l+2) = make_double2(n2,n3);          \
    if (is63) Ww[256] = n4;                                                 \
    Ww += LPAD;                                                             \
    if ((j)==5) {                                                           \
      double part=(n0+n1)+(n2+n3); if (is63) part+=n4;                      \
      Sfull = full64(part);                                                 \
    }                                                                       \
    if ((j)==7) {                                                           \
      double Su = readlane63_f64(Sfull);                                    \
      int ex = (__double2hiint(Su)>>20) & 0x7FF;                            \
      int e = (ex==0) ? -512 : (ex-1023);                                   \
      e = e < -900 ? -900 : (e > 900 ? 900 : e);                            \
      scNext = pow2i(-e);                                                   \
      if (REV && l==0 && (i)+1 < TT) EbB[((i)+1)>>3] = e;                   \
    }                                                                       \
    a0=n0; a1=n1; a2=n2; a3=n3; a4=n4;                                      \
    int inx = ((i)+8 < TT) ? (i)+8 : TT-1;                                  \
    int pcn = REV ? (TT-1-inx) : inx;                                       \
    pbB[j]=pBp[pcn]; pb1[j]=p1p[pcn]; pb3[j]=p3p[pcn];                      \
  }

    STEP(0,0,true,false)  STEP(1,1,false,false) STEP(2,2,false,false)
    STEP(3,3,false,false) STEP(4,4,false,false) STEP(5,5,false,false)
    STEP(6,6,false,false) STEP(7,7,false,false)
    for (int i0=8; i0<TT-SS; i0+=8) {
        #pragma unroll
        for (int j=0;j<8;++j) STEP(i0+j, j, false, false)
    }
    for (int i0=TT-SS; i0<TT; i0+=8) {
        #pragma unroll
        for (int j=0;j<8;++j) STEP(i0+j, j, false, true)
    }
#undef STEP
}

__global__ __launch_bounds__(64)
void ctc_scan(const float* __restrict__ P, const int* __restrict__ seqg,
              const int* __restrict__ blankp, double* __restrict__ Wa,
              double* __restrict__ Wb, int* __restrict__ Eb)
{
    const int bx = blockIdx.x, l = threadIdx.x;
    const int blank = blankp[0];
    if (bx < BB) scan_body<false>(bx,      l, P, seqg, blank, Wa, Eb);
    else         scan_body<true >(bx - BB, l, P, seqg, blank, Wb, Eb);
}

// =========================== parallel combine ===========================
// Block (b, q): one wave handles t = 8q .. 8q+7.  i = T-1-t.
__global__ __launch_bounds__(64)
void ctc_combine(const double* __restrict__ Wa, const double* __restrict__ Wb,
                 const int* __restrict__ Eb, const int* __restrict__ seqg,
                 double* __restrict__ Lq)
{
    const int b = blockIdx.x, q = blockIdx.y, l = threadIdx.x;
    const bool is63 = (l == 63);
    const int* sq = seqg + b*SS;
    // beta-orientation skip masks (same as the beta scan)
    const int r1 = sq[SS-1-2*l], r3 = sq[SS-2-2*l];
    const int ip = (l==0) ? 0 : (SS-2*l);
    const double m1 = (l==0) ? 1.0 : ((r1 != sq[ip]) ? 1.0 : 0.0);
    const double m3 = (r3 != r1) ? 1.0 : 0.0;
    const int tm0=(4*l+769)>>1, tm1=(4*l+770)>>1, tm2=(4*l+771)>>1, tm3=(4*l+772)>>1;

    const double* WaB = Wa + (size_t)b*TT*LPAD;
    const double* WbB = Wb + (size_t)b*TT*LPAD;
    const int t0 = q*8;

    // preload R for the first step: R_i0 = sum of w_b row i0 = T-1-t0
    {
        const double* rw = WbB + (size_t)(TT-1-t0)*LPAD;
        double2 x01 = *reinterpret_cast<const double2*>(rw + 4*l);
        double2 x23 = *reinterpret_cast<const double2*>(rw + 4*l + 2);
        double rnp = (x01.x+x01.y)+(x23.x+x23.y);
        if (is63) rnp += rw[256];
        // Rcur valid on lane 63 only (that's where it's consumed)
        double Rcur = full64(rnp);
        double acc = 0.0;

        #pragma unroll
        for (int k=0; k<8; ++k) {
            const int t = t0 + k;
            const int i = TT-1-t;
            // alpha row t, reversed fragment: lane l holds w_a[252-4l .. 256-4l]
            const double* ar = WaB + (size_t)t*LPAD + (252 - 4*l);
            double2 a01 = *reinterpret_cast<const double2*>(ar);
            double2 a23 = *reinterpret_cast<const double2*>(ar + 2);
            double ar4 = ar[4];

            double u0,u1,u2,u3,u4, rnext = 0.0;
            if (i > 0) {
                const double* rw = WbB + (size_t)(i-1)*LPAD;
                double2 b01 = *reinterpret_cast<const double2*>(rw + 4*l);
                double2 b23 = *reinterpret_cast<const double2*>(rw + 4*l + 2);
                double b4 = rw[256];                     // uniform broadcast
                double e3u = shfl_up1_f64(b23.y);        // w_b[4l-1]
                u0 = b01.x + e3u;
                u1 = (b01.y + b01.x) + m1*e3u;
                u2 = b23.x + b01.y;
                u3 = (b23.y + b23.x) + m3*b01.y;
                u4 = b4 + b23.y;                         // s'=256 (lane 63)
                if (i >= TT - SS) {
                    if (i >= tm0) u0 = 0.0;
                    if (i >= tm1) u1 = 0.0;
                    if (i >= tm2) u2 = 0.0;
                    if (i >= tm3) u3 = 0.0;
                }
                rnext = (b01.x+b01.y)+(b23.x+b23.y);     // R_{i-1} partial
                if (is63) rnext += b4;
            } else {
                u0 = (l==0)?1.0:0.0; u1 = u0; u2=0.0; u3=0.0; u4=0.0;
            }
            // D = sum_s' w_a[256-s',t] * U[s'] ; S = sum w_a row t
            double trp = ar4*u0 + a23.y*u1 + a23.x*u2 + a01.y*u3;
            if (is63) trp += a01.x*u4;
            double sap = (a01.y + a23.x) + (a23.y + ar4);
            if (is63) sap += a01.x;

            double D  = full64(trp);
            double S  = full64(sap);
            double Rn = full64(rnext);
            if (is63) {
                double e = (i > 0 && (i & 7) == 0) ? (double)Eb[b*64 + (i>>3)] : 0.0;
                acc += log(fmax(D, 1e-300)) - log(fmax(S*Rcur, 1e-300)) - e*M_LN2;
            }
            Rcur = Rn;   // lane-63-valid, lane-63-consumed
        }
        if (is63) Lq[b*64 + q] = acc;
    }
}

__global__ __launch_bounds__(256)
void ctc_final(const double* __restrict__ Lq, float* __restrict__ out)
{
    const int t = threadIdx.x;        // 256 threads, 8192 inputs
    double v = 0.0;
    #pragma unroll
    for (int k=0;k<32;++k) v += Lq[t + 256*k];
    double s = full64(v);
    __shared__ double w[4];
    if ((t & 63) == 63) w[t>>6] = s;
    __syncthreads();
    if (t == 0) out[0] = (float)(-(w[0]+w[1]+w[2]+w[3]));
}

extern "C" void kernel_launch(void* const* d_in, const int* in_sizes, int n_in,
                              void* d_out, int out_size, void* d_ws, size_t ws_size,
                              hipStream_t stream)
{
    const float* P     = (const float*)d_in[0];   // params (B,C,T) fp32
    const int*   seq   = (const int*)  d_in[1];   // (B,S) int32
    // d_in[2] = lengths (unused by the reference computation)
    const int*   blank = (const int*)  d_in[3];   // scalar int

    // ws layout: Wa rows | Wb rows | Lq | Eb    (~272.7 MB)
    double* Wa = (double*)d_ws;
    double* Wb = Wa + (size_t)BB*TT*LPAD;
    double* Lq = Wb + (size_t)BB*TT*LPAD;         // 8192 doubles
    int*    Eb = (int*)(Lq + (size_t)BB*64);      // 8192 ints
    (void)ws_size; (void)in_sizes; (void)n_in; (void)out_size;

    ctc_scan<<<2*BB, 64, 0, stream>>>(P, seq, blank, Wa, Wb, Eb);
    ctc_combine<<<dim3(BB, 64), 64, 0, stream>>>(Wa, Wb, Eb, seq, Lq);
    ctc_final<<<1, 256, 0, stream>>>(Lq, (float*)d_out);
}

// Round 6
// 85.278 us; speedup vs baseline: 8.2366x; 1.5800x over previous
//
#include <hip/hip_runtime.h>
#include <math.h>

// CTC loss (per-step-normalized fwd/bwd), B=128, C=512, T=512, S=128, L=257.
// Round-6: rows stored (and recursion computed) in FP32 with exact power-of-2
// per-8-step rescale -> both row buffers = 136 MB, fits the 256 MiB Infinity
// Cache (round-5's 273 MB of fp64 rows spilled: 266 MB HBM WRITE_SIZE at the
// ~3.1 TB/s write ceiling). Combine identity (validated rounds 4-5):
//   lh_t = sigma_i * D / (S_t * R_i),  i = T-1-t
//   D = sum_s' w_a[256-s',t] * U_i[s'],  U_i = masked shift of w_b row i-1,
//   S_t = sum w_a row t,  R_i = sum w_b row i,  sigma_i = 2^-e_g at i=8g.
// All embedded scales are powers of 2 and cancel exactly; logs accumulate in
// fp64. All quantities >= 0, logs clamped -> no NaN possible.

#define BB 128
#define CC 512
#define TT 512
#define SS 128
#define LL 257
#define LPAD 260    // floats per row (1040 B, 16B-aligned float4 at 4l)

// ---- fp32 DPP helpers (gfx9 controls; validated on gfx950 rounds 3-5) ----
template<int CTRL>
__device__ __forceinline__ float dpp0_f32(float x){
    int v = __builtin_bit_cast(int, x);
    int r = __builtin_amdgcn_update_dpp(0, v, CTRL, 0xF, 0xF, true);
    return __builtin_bit_cast(float, r);
}
__device__ __forceinline__ float shfl_up1_f32(float x){ return dpp0_f32<0x138>(x); }
__device__ __forceinline__ float red8f(float x){
    x += dpp0_f32<0x111>(x);  // row_shr:1
    x += dpp0_f32<0x112>(x);  // row_shr:2
    x += dpp0_f32<0x114>(x);  // row_shr:4
    return x;
}
__device__ __forceinline__ float tail3f(float x){   // full 64-lane sum -> lane 63
    x += dpp0_f32<0x118>(x);  // row_shr:8
    x += dpp0_f32<0x142>(x);  // row_bcast:15
    x += dpp0_f32<0x143>(x);  // row_bcast:31
    return x;
}
__device__ __forceinline__ float full64f(float x){ return tail3f(red8f(x)); }
__device__ __forceinline__ float readlane63_f32(float x){
    int v = __builtin_bit_cast(int, x);
    return __builtin_bit_cast(float, __builtin_amdgcn_readlane(v, 63));
}
__device__ __forceinline__ float pow2if(int e){     // e in [-126,127], exact
    return __builtin_bit_cast(float, (127 + e) << 23);
}
// ---- fp64 DPP (final reductions only) ----
template<int CTRL>
__device__ __forceinline__ double dpp0_f64(double x){
    int2 v = __builtin_bit_cast(int2, x);
    int2 r;
    r.x = __builtin_amdgcn_update_dpp(0, v.x, CTRL, 0xF, 0xF, true);
    r.y = __builtin_amdgcn_update_dpp(0, v.y, CTRL, 0xF, 0xF, true);
    return __builtin_bit_cast(double, r);
}
__device__ __forceinline__ double full64d(double x){
    x += dpp0_f64<0x111>(x); x += dpp0_f64<0x112>(x); x += dpp0_f64<0x114>(x);
    x += dpp0_f64<0x118>(x); x += dpp0_f64<0x142>(x); x += dpp0_f64<0x143>(x);
    return x;
}

// =================== row-storing scan (both roles, fp32) ===================
template<bool REV>
__device__ __forceinline__ void scan_body(
    int b, int l, const float* __restrict__ P, const int* __restrict__ seqg,
    int blank, float* __restrict__ W, int* __restrict__ Eb)
{
    const bool is63 = (l == 63);
    const float* Pb = P + (size_t)b * (CC*TT);
    const int* sq = seqg + b*SS;

    int r1, r3; float m1, m3;
    if (!REV) {
        r1 = sq[2*l]; r3 = sq[2*l+1];
        int ip = (l==0) ? 0 : (2*l-1);
        m1 = (l==0) ? 1.f : ((r1 != sq[ip]) ? 1.f : 0.f);
        m3 = (r3 != r1) ? 1.f : 0.f;
    } else {
        r1 = sq[SS-1-2*l]; r3 = sq[SS-2-2*l];
        int ip = (l==0) ? 0 : (SS-2*l);
        m1 = (l==0) ? 1.f : ((r1 != sq[ip]) ? 1.f : 0.f);
        m3 = (r3 != r1) ? 1.f : 0.f;
    }
    const float* pBp = Pb + (size_t)blank*TT;
    const float* p1p = Pb + (size_t)r1*TT;
    const float* p3p = Pb + (size_t)r3*TT;
    float* Ww = W + (size_t)b*TT*LPAD;
    int* EbB = Eb + b*64;

    // start-mask thresholds: state s masked at step i iff i >= (s+769)>>1
    const int tm0=(4*l+769)>>1, tm1=(4*l+770)>>1, tm2=(4*l+771)>>1, tm3=(4*l+772)>>1;

    float pbB[8], pb1[8], pb3[8];
    #pragma unroll
    for (int j=0;j<8;++j){
        int pc = REV ? (TT-1-j) : j;
        pbB[j]=pBp[pc]; pb1[j]=p1p[pc]; pb3[j]=p3p[pc];
    }

    float a0=0.f,a1=0.f,a2=0.f,a3=0.f,a4=0.f;
    float scNext = 1.f, Sfull = 0.f;
    const float u0i = (l==0) ? 1.f : 0.f;

#define STEP(i, j, FIRSTF, MASKF)                                           \
  {                                                                         \
    float u0,u1,u2,u3,u4;                                                   \
    if (FIRSTF) { u0=u0i; u1=u0i; u2=0.f; u3=0.f; u4=0.f; }                 \
    else {                                                                  \
      float e3u = shfl_up1_f32(a3);                                         \
      u0 = a0 + e3u; u1 = (a1+a0) + m1*e3u; u2 = a2+a1;                     \
      u3 = (a3+a2) + m3*a1; u4 = a4+a3;                                     \
      if (MASKF) {                                                          \
        if ((i) >= tm0) u0 = 0.f;                                           \
        if ((i) >= tm1) u1 = 0.f;                                           \
        if ((i) >= tm2) u2 = 0.f;                                           \
        if ((i) >= tm3) u3 = 0.f;                                           \
      }                                                                     \
    }                                                                       \
    float pB=pbB[j], pq=pb1[j], pr=pb3[j];                                  \
    if ((j)==0) { pB*=scNext; pq*=scNext; pr*=scNext; }                     \
    float n0=u0*pB, n1=u1*pq, n2=u2*pB, n3=u3*pr, n4=u4*pB;                 \
    *reinterpret_cast<float4*>(Ww + 4*l) = make_float4(n0,n1,n2,n3);        \
    if (is63) Ww[256] = n4;                                                 \
    Ww += LPAD;                                                             \
    if ((j)==5) {                                                           \
      float part=(n0+n1)+(n2+n3); if (is63) part+=n4;                       \
      Sfull = full64f(part);                                                \
    }                                                                       \
    if ((j)==7) {                                                           \
      float Su = readlane63_f32(Sfull);                                     \
      int ex = (__builtin_bit_cast(int, Su) >> 23) & 0xFF;                  \
      int e = (ex==0) ? 0 : (ex-127);                                       \
      e = e < -120 ? -120 : (e > 120 ? 120 : e);                            \
      scNext = pow2if(-e);                                                  \
      if (REV && l==0 && (i)+1 < TT) EbB[((i)+1)>>3] = e;                   \
    }                                                                       \
    a0=n0; a1=n1; a2=n2; a3=n3; a4=n4;                                      \
    int inx = ((i)+8 < TT) ? (i)+8 : TT-1;                                  \
    int pcn = REV ? (TT-1-inx) : inx;                                       \
    pbB[j]=pBp[pcn]; pb1[j]=p1p[pcn]; pb3[j]=p3p[pcn];                      \
  }

    STEP(0,0,true,false)  STEP(1,1,false,false) STEP(2,2,false,false)
    STEP(3,3,false,false) STEP(4,4,false,false) STEP(5,5,false,false)
    STEP(6,6,false,false) STEP(7,7,false,false)
    for (int i0=8; i0<TT-SS; i0+=8) {
        #pragma unroll
        for (int j=0;j<8;++j) STEP(i0+j, j, false, false)
    }
    for (int i0=TT-SS; i0<TT; i0+=8) {
        #pragma unroll
        for (int j=0;j<8;++j) STEP(i0+j, j, false, true)
    }
#undef STEP
}

__global__ __launch_bounds__(64)
void ctc_scan(const float* __restrict__ P, const int* __restrict__ seqg,
              const int* __restrict__ blankp, float* __restrict__ Wa,
              float* __restrict__ Wb, int* __restrict__ Eb)
{
    const int bx = blockIdx.x, l = threadIdx.x;
    const int blank = blankp[0];
    if (bx < BB) scan_body<false>(bx,      l, P, seqg, blank, Wa, Eb);
    else         scan_body<true >(bx - BB, l, P, seqg, blank, Wb, Eb);
}

// =========================== parallel combine ===========================
// Block (b, q): one wave handles t = 8q .. 8q+7.  i = T-1-t.
__global__ __launch_bounds__(64)
void ctc_combine(const float* __restrict__ Wa, const float* __restrict__ Wb,
                 const int* __restrict__ Eb, const int* __restrict__ seqg,
                 double* __restrict__ Lq)
{
    const int b = blockIdx.x, q = blockIdx.y, l = threadIdx.x;
    const bool is63 = (l == 63);
    const int* sq = seqg + b*SS;
    // beta-orientation skip masks (same as the beta scan)
    const int r1 = sq[SS-1-2*l], r3 = sq[SS-2-2*l];
    const int ip = (l==0) ? 0 : (SS-2*l);
    const float m1 = (l==0) ? 1.f : ((r1 != sq[ip]) ? 1.f : 0.f);
    const float m3 = (r3 != r1) ? 1.f : 0.f;
    const int tm0=(4*l+769)>>1, tm1=(4*l+770)>>1, tm2=(4*l+771)>>1, tm3=(4*l+772)>>1;

    const float* WaB = Wa + (size_t)b*TT*LPAD;
    const float* WbB = Wb + (size_t)b*TT*LPAD;
    const int t0 = q*8;

    // preload R for the first step: R_i0 = sum of w_b row i0 = T-1-t0
    float Rcur;
    {
        const float* rw = WbB + (size_t)(TT-1-t0)*LPAD;
        float4 x = *reinterpret_cast<const float4*>(rw + 4*l);
        float rnp = (x.x+x.y)+(x.z+x.w);
        if (is63) rnp += rw[256];
        Rcur = full64f(rnp);          // valid on lane 63 (consumed there)
    }
    double acc = 0.0;

    #pragma unroll
    for (int k=0; k<8; ++k) {
        const int t = t0 + k;
        const int i = TT-1-t;
        // alpha row t, reversed fragment: lane l holds w_a[252-4l .. 256-4l]
        const float* ar = WaB + (size_t)t*LPAD + (252 - 4*l);
        float4 av = *reinterpret_cast<const float4*>(ar);
        float ar4 = ar[4];

        float u0,u1,u2,u3,u4, rnext = 0.f;
        if (i > 0) {
            const float* rw = WbB + (size_t)(i-1)*LPAD;
            float4 bv = *reinterpret_cast<const float4*>(rw + 4*l);
            float b4 = rw[256];                     // uniform broadcast
            float e3u = shfl_up1_f32(bv.w);         // w_b[4l-1]
            u0 = bv.x + e3u;
            u1 = (bv.y + bv.x) + m1*e3u;
            u2 = bv.z + bv.y;
            u3 = (bv.w + bv.z) + m3*bv.y;
            u4 = b4 + bv.w;                         // s'=256 (lane 63)
            if (i >= TT - SS) {
                if (i >= tm0) u0 = 0.f;
                if (i >= tm1) u1 = 0.f;
                if (i >= tm2) u2 = 0.f;
                if (i >= tm3) u3 = 0.f;
            }
            rnext = (bv.x+bv.y)+(bv.z+bv.w);        // R_{i-1} partial
            if (is63) rnext += b4;
        } else {
            u0 = (l==0)?1.f:0.f; u1 = u0; u2=0.f; u3=0.f; u4=0.f;
        }
        // D = sum_s' w_a[256-s',t]*U[s'] ; S = sum w_a row t
        float trp = ar4*u0 + av.w*u1 + av.z*u2 + av.y*u3;
        if (is63) trp += av.x*u4;
        float sap = (av.y + av.z) + (av.w + ar4);
        if (is63) sap += av.x;

        float D  = full64f(trp);
        float S  = full64f(sap);
        float Rn = full64f(rnext);
        if (is63) {
            double e = (i > 0 && (i & 7) == 0) ? (double)Eb[b*64 + (i>>3)] : 0.0;
            double dd = fmax((double)D, 1e-300);
            double sr = fmax((double)S * (double)Rcur, 1e-300);
            acc += log(dd) - log(sr) - e*M_LN2;
        }
        Rcur = Rn;   // lane-63-valid, lane-63-consumed
    }
    if (is63) Lq[b*64 + q] = acc;
}

__global__ __launch_bounds__(256)
void ctc_final(const double* __restrict__ Lq, float* __restrict__ out)
{
    const int t = threadIdx.x;        // 256 threads, 8192 inputs
    double v = 0.0;
    #pragma unroll
    for (int k=0;k<32;++k) v += Lq[t + 256*k];
    double s = full64d(v);
    __shared__ double w[4];
    if ((t & 63) == 63) w[t>>6] = s;
    __syncthreads();
    if (t == 0) out[0] = (float)(-(w[0]+w[1]+w[2]+w[3]));
}

extern "C" void kernel_launch(void* const* d_in, const int* in_sizes, int n_in,
                              void* d_out, int out_size, void* d_ws, size_t ws_size,
                              hipStream_t stream)
{
    const float* P     = (const float*)d_in[0];   // params (B,C,T) fp32
    const int*   seq   = (const int*)  d_in[1];   // (B,S) int32
    // d_in[2] = lengths (unused by the reference computation)
    const int*   blank = (const int*)  d_in[3];   // scalar int

    // ws layout: Wa rows (68.2 MB) | Wb rows (68.2 MB) | Lq | Eb  (~136.5 MB)
    float* Wa = (float*)d_ws;
    float* Wb = Wa + (size_t)BB*TT*LPAD;
    double* Lq = (double*)(Wb + (size_t)BB*TT*LPAD);   // 8192 doubles
    int*    Eb = (int*)(Lq + (size_t)BB*64);           // 8192 ints
    (void)ws_size; (void)in_sizes; (void)n_in; (void)out_size;

    ctc_scan<<<2*BB, 64, 0, stream>>>(P, seq, blank, Wa, Wb, Eb);
    ctc_combine<<<dim3(BB, 64), 64, 0, stream>>>(Wa, Wb, Eb, seq, Lq);
    ctc_final<<<1, 256, 0, stream>>>(Lq, (float*)d_out);
}